// Round 5
// baseline (61.234 us; speedup 1.0000x reference)
//
#include <hip/hip_runtime.h>

typedef __attribute__((ext_vector_type(8))) short bf16x8;
typedef __attribute__((ext_vector_type(4))) float f32x4;

constexpr int TN = 8192;   // tokens
constexpr int DN = 4096;   // model dim
constexpr int EN = 64;     // experts

constexpr int BM  = 32;        // rows per block
constexpr int KC  = 256;       // k per staged chunk (8 K32 slots = 8 waves)
constexpr int NT  = DN / KC;   // 16 chunks
constexpr int NS  = DN / 32;   // 128 MFMA k-steps total
constexpr int KPB = KC + 8;    // A k-stride bf16 (528B row: lane stride 4 banks -> free)

__device__ __forceinline__ unsigned short f2bf(float f) {  // RNE f32->bf16
    unsigned u = __builtin_bit_cast(unsigned, f);
    u += 0x7FFFu + ((u >> 16) & 1u);
    return (unsigned short)(u >> 16);
}
__device__ __forceinline__ float bf2f(unsigned short h) {
    unsigned u = ((unsigned)h) << 16;
    return __builtin_bit_cast(float, u);
}

// Kernel 0: split wg into hi/lo bf16 planes in MFMA-fragment order:
// BF[p][s][et][lane*8+j] = plane_p( wg[et*16+(lane&15)][s*32+(lane>>4)*8+j] )
// so a wave's B-fragment load in the GEMM is base + lane*16B (1KB coalesced).
__global__ __launch_bounds__(256)
void wg_frag_kernel(const float* __restrict__ wg, unsigned short* __restrict__ BF) {
    const int gid = blockIdx.x * 256 + threadIdx.x;  // 65536 items
    const int l  = gid & 63;
    const int et = (gid >> 6) & 3;
    const int s  = (gid >> 8) & (NS - 1);
    const int p  = gid >> 15;
    const int e  = et * 16 + (l & 15);
    const int k  = s * 32 + (l >> 4) * 8;

    const float* src = wg + (size_t)e * DN + k;
    float4 v0 = *reinterpret_cast<const float4*>(src);
    float4 v1 = *reinterpret_cast<const float4*>(src + 4);
    float f[8] = {v0.x, v0.y, v0.z, v0.w, v1.x, v1.y, v1.z, v1.w};
    unsigned short o[8];
#pragma unroll
    for (int j = 0; j < 8; ++j) {
        unsigned short h = f2bf(f[j]);
        o[j] = p ? f2bf(f[j] - bf2f(h)) : h;
    }
    unsigned short* dst = BF + (((size_t)p * NS + s) * 4 + et) * 512 + (size_t)l * 8;
    *reinterpret_cast<ushort4*>(dst)     = make_ushort4(o[0], o[1], o[2], o[3]);
    *reinterpret_cast<ushort4*>(dst + 4) = make_ushort4(o[4], o[5], o[6], o[7]);
}

// Kernel 1: fused split-bf16 MFMA GEMM + top-1 softmax. Grid = 256 (1/CU),
// 512 threads = 8 waves; wave w owns K-slot w of each 256-wide chunk and
// computes BOTH 16-row halves (no duplicated B loads). x staged fp32->hi/lo
// bf16 into double-buffered LDS; B fragments are coalesced 16B/lane loads
// from pre-swizzled BF (L2-hot, 1MB). logits = hh+lh+hl+ll MFMA products.
__global__ __launch_bounds__(512, 2)
void gate_fused_kernel(const float* __restrict__ x,
                       const unsigned short* __restrict__ BF,
                       float* __restrict__ out) {
    // A[2][2][32][KPB]u16 = 67584 B; L[8][32][68]f32 = 69632 B (aliased)
    __shared__ __align__(16) char smem[8 * BM * 68 * 4];
    typedef unsigned short AType[2][BM][KPB];
    AType* A = reinterpret_cast<AType*>(smem);
    typedef float LType[BM][68];
    LType* L = reinterpret_cast<LType*>(smem);

    const int tid  = threadIdx.x;
    const int lane = tid & 63;
    const int kq   = tid >> 6;          // wave id = K32 slot 0..7
    const int r0   = blockIdx.x * BM;

    // staging: 16 threads/row, 16 contiguous floats (64B) each
    const int srow = tid >> 4;          // 0..31
    const int skf  = (tid & 15) * 16;   // float offset within chunk
    const float* xp = x + (size_t)(r0 + srow) * DN + skf;

    const int fr  = lane & 15;          // fragment row/col
    const int fko = (lane >> 4) * 8;    // fragment k offset within K=32

    f32x4 acc[2][4] = {};

    float4 xv[4];
    auto g_load = [&](int t) {
        const float* p = xp + (size_t)t * KC;
        xv[0] = *reinterpret_cast<const float4*>(p);
        xv[1] = *reinterpret_cast<const float4*>(p + 4);
        xv[2] = *reinterpret_cast<const float4*>(p + 8);
        xv[3] = *reinterpret_cast<const float4*>(p + 12);
    };
    auto l_store = [&](int b) {
        float f[16] = {xv[0].x, xv[0].y, xv[0].z, xv[0].w,
                       xv[1].x, xv[1].y, xv[1].z, xv[1].w,
                       xv[2].x, xv[2].y, xv[2].z, xv[2].w,
                       xv[3].x, xv[3].y, xv[3].z, xv[3].w};
        bf16x8 vh[2], vl[2];
#pragma unroll
        for (int j = 0; j < 16; ++j) {
            unsigned short hh = f2bf(f[j]);
            vh[j >> 3][j & 7] = (short)hh;
            vl[j >> 3][j & 7] = (short)f2bf(f[j] - bf2f(hh));
        }
        *reinterpret_cast<bf16x8*>(&A[b][0][srow][skf])     = vh[0];
        *reinterpret_cast<bf16x8*>(&A[b][0][srow][skf + 8]) = vh[1];
        *reinterpret_cast<bf16x8*>(&A[b][1][srow][skf])     = vl[0];
        *reinterpret_cast<bf16x8*>(&A[b][1][srow][skf + 8]) = vl[1];
    };
    auto compute = [&](int b, int t) {
        const int s = t * 8 + kq;       // this wave's global K32 step
        const unsigned short* bp = BF + (size_t)s * 2048 + (size_t)lane * 8;
        bf16x8 ah[2], al[2];
#pragma unroll
        for (int rh = 0; rh < 2; ++rh) {
            ah[rh] = *reinterpret_cast<const bf16x8*>(&A[b][0][rh * 16 + fr][kq * 32 + fko]);
            al[rh] = *reinterpret_cast<const bf16x8*>(&A[b][1][rh * 16 + fr][kq * 32 + fko]);
        }
#pragma unroll
        for (int et = 0; et < 4; ++et) {
            bf16x8 bh = *reinterpret_cast<const bf16x8*>(bp + et * 512);
            bf16x8 bl = *reinterpret_cast<const bf16x8*>(bp + (size_t)NS * 2048 + et * 512);
#pragma unroll
            for (int rh = 0; rh < 2; ++rh) {
                acc[rh][et] = __builtin_amdgcn_mfma_f32_16x16x32_bf16(ah[rh], bh, acc[rh][et], 0, 0, 0);
                acc[rh][et] = __builtin_amdgcn_mfma_f32_16x16x32_bf16(al[rh], bh, acc[rh][et], 0, 0, 0);
                acc[rh][et] = __builtin_amdgcn_mfma_f32_16x16x32_bf16(ah[rh], bl, acc[rh][et], 0, 0, 0);
                acc[rh][et] = __builtin_amdgcn_mfma_f32_16x16x32_bf16(al[rh], bl, acc[rh][et], 0, 0, 0);
            }
        }
    };

    g_load(0);
    l_store(0);
    __syncthreads();
    int cur = 0;
    for (int t = 0; t < NT; ++t) {
        if (t + 1 < NT) g_load(t + 1);   // issue early: HBM hides under compute
        compute(cur, t);
        if (t + 1 < NT) {
            l_store(cur ^ 1);
            __syncthreads();
            cur ^= 1;
        }
    }

    // epilogue: per-slot partial logits into LDS (alias A), fused top-1 softmax
    __syncthreads();  // all waves done reading A before aliasing as L
#pragma unroll
    for (int rh = 0; rh < 2; ++rh)
#pragma unroll
        for (int et = 0; et < 4; ++et)
#pragma unroll
            for (int r = 0; r < 4; ++r)
                // C/D layout: col = lane&15, row = (lane>>4)*4 + reg  [m89]
                L[kq][rh * 16 + (lane >> 4) * 4 + r][et * 16 + fr] = acc[rh][et][r];
    __syncthreads();

    {
        const int row = tid >> 4;   // 0..31
        const int eg  = tid & 15;   // 4 experts each
        float v[4];
#pragma unroll
        for (int j = 0; j < 4; ++j) {
            float s = L[0][row][eg * 4 + j];
#pragma unroll
            for (int q = 1; q < 8; ++q) s += L[q][row][eg * 4 + j];
            v[j] = s;
        }
        float m = v[0];
        int idx = eg * 4;
#pragma unroll
        for (int j = 1; j < 4; ++j)
            if (v[j] > m) { m = v[j]; idx = eg * 4 + j; }  // strict >: first occurrence
#pragma unroll
        for (int d = 1; d < 16; d <<= 1) {
            float om = __shfl_xor(m, d);
            int   oi = __shfl_xor(idx, d);
            if (om > m || (om == m && oi < idx)) { m = om; idx = oi; }
        }
        float s = 0.0f;
#pragma unroll
        for (int j = 0; j < 4; ++j) s += __expf(v[j] - m);
#pragma unroll
        for (int d = 1; d < 16; d <<= 1) s += __shfl_xor(s, d);
        if (eg == 0) {
            out[r0 + row]      = (float)idx;     // argmax index
            out[TN + r0 + row] = 1.0f / s;       // max gate = 1/sum(exp(l-lmax))
        }
    }
}

extern "C" void kernel_launch(void* const* d_in, const int* in_sizes, int n_in,
                              void* d_out, int out_size, void* d_ws, size_t ws_size,
                              hipStream_t stream) {
    const float* x  = (const float*)d_in[0];
    const float* wg = (const float*)d_in[1];
    float* out = (float*)d_out;

    unsigned short* BF = (unsigned short*)d_ws;  // 1 MB fragment-ordered hi/lo

    wg_frag_kernel<<<dim3(256), dim3(256), 0, stream>>>(wg, BF);
    gate_fused_kernel<<<dim3(TN / BM), dim3(512), 0, stream>>>(x, BF, out);
}

// Round 6
// 46.136 us; speedup vs baseline: 1.3272x; 1.3272x over previous
//
#include <hip/hip_runtime.h>

typedef __attribute__((ext_vector_type(8))) short bf16x8;
typedef __attribute__((ext_vector_type(4))) float f32x4;

constexpr int TN = 8192;   // tokens
constexpr int DN = 4096;   // model dim
constexpr int EN = 64;     // experts

constexpr int BM  = 16;        // rows per block
constexpr int KC  = 128;       // k per staged chunk (4 K32 slots = 4 waves)
constexpr int NT  = DN / KC;   // 32 chunks
constexpr int NS  = DN / 32;   // 128 MFMA k-steps total
constexpr int KPB = KC + 8;    // A k-stride bf16 (272B row: odd 16B-quad stride -> uniform banks)

__device__ __forceinline__ unsigned short f2bf(float f) {  // RNE f32->bf16
    unsigned u = __builtin_bit_cast(unsigned, f);
    u += 0x7FFFu + ((u >> 16) & 1u);
    return (unsigned short)(u >> 16);
}
__device__ __forceinline__ float bf2f(unsigned short h) {
    unsigned u = ((unsigned)h) << 16;
    return __builtin_bit_cast(float, u);
}

// Kernel 0: split wg into hi/lo bf16 planes in MFMA-fragment order:
// BF[p][s][et][lane*8+j] = plane_p( wg[et*16+(lane&15)][s*32+(lane>>4)*8+j] )
// so a wave's B-fragment load in the GEMM is base + lane*16B (1KB coalesced).
__global__ __launch_bounds__(256)
void wg_frag_kernel(const float* __restrict__ wg, unsigned short* __restrict__ BF) {
    const int gid = blockIdx.x * 256 + threadIdx.x;  // 65536 items
    const int l  = gid & 63;
    const int et = (gid >> 6) & 3;
    const int s  = (gid >> 8) & (NS - 1);
    const int p  = gid >> 15;
    const int e  = et * 16 + (l & 15);
    const int k  = s * 32 + (l >> 4) * 8;

    const float* src = wg + (size_t)e * DN + k;
    float4 v0 = *reinterpret_cast<const float4*>(src);
    float4 v1 = *reinterpret_cast<const float4*>(src + 4);
    float f[8] = {v0.x, v0.y, v0.z, v0.w, v1.x, v1.y, v1.z, v1.w};
    unsigned short o[8];
#pragma unroll
    for (int j = 0; j < 8; ++j) {
        unsigned short h = f2bf(f[j]);
        o[j] = p ? f2bf(f[j] - bf2f(h)) : h;
    }
    unsigned short* dst = BF + (((size_t)p * NS + s) * 4 + et) * 512 + (size_t)l * 8;
    *reinterpret_cast<ushort4*>(dst)     = make_ushort4(o[0], o[1], o[2], o[3]);
    *reinterpret_cast<ushort4*>(dst + 4) = make_ushort4(o[4], o[5], o[6], o[7]);
}

// Kernel 1: fused split-bf16 MFMA GEMM + top-1 softmax.
// Grid = 512 (2 blocks/CU), 256 threads = 4 waves; wave = K32 slot within
// each 128-wide chunk. Depth-2 register x-prefetch + B-register prefetch
// issued FIRST each iter (so compute's B vmcnt-wait never forces fresh x).
__global__ __launch_bounds__(256, 2)
void gate_fused_kernel(const float* __restrict__ x,
                       const unsigned short* __restrict__ BF,
                       float* __restrict__ out) {
    // A[2 buf][2 plane][16][KPB]u16 = 17408 B; L[4][16][68]f32 = 17408 B alias
    __shared__ __align__(16) char smem[17408];
    typedef unsigned short AType[2][BM][KPB];
    AType* A = reinterpret_cast<AType*>(smem);
    typedef float LType[BM][68];
    LType* L = reinterpret_cast<LType*>(smem);

    const int tid  = threadIdx.x;
    const int lane = tid & 63;
    const int kq   = tid >> 6;          // wave id = K32 slot 0..3
    const int r0   = blockIdx.x * BM;

    // staging: 16 threads/row, 8 contiguous floats (32B) each
    const int srow = tid >> 4;          // 0..15
    const int skf  = (tid & 15) * 8;    // float offset within chunk
    const float* xp = x + (size_t)(r0 + srow) * DN + skf;

    const int fr  = lane & 15;          // fragment row/col
    const int fko = (lane >> 4) * 8;    // fragment k offset within K=32
    const int kloc = kq * 32 + fko;

    f32x4 acc[4] = {};

    float4 X0[2], X1[2];                // ping-pong x prefetch (depth 2)
    bf16x8 B0[8], B1[8];                // ping-pong B prefetch ([et]=hi, [4+et]=lo)

    auto loadX = [&](float4 (&X)[2], int t) {
        const float* p = xp + (size_t)t * KC;
        X[0] = *reinterpret_cast<const float4*>(p);
        X[1] = *reinterpret_cast<const float4*>(p + 4);
    };
    auto loadB = [&](bf16x8 (&B)[8], int t) {
        const int s = t * 4 + kq;
        const unsigned short* bp = BF + (size_t)s * 2048 + (size_t)lane * 8;
#pragma unroll
        for (int et = 0; et < 4; ++et)
            B[et] = *reinterpret_cast<const bf16x8*>(bp + et * 512);
#pragma unroll
        for (int et = 0; et < 4; ++et)
            B[4 + et] = *reinterpret_cast<const bf16x8*>(bp + (size_t)NS * 2048 + et * 512);
    };
    auto stage = [&](int b, float4 (&X)[2]) {
        float f[8] = {X[0].x, X[0].y, X[0].z, X[0].w,
                      X[1].x, X[1].y, X[1].z, X[1].w};
        bf16x8 vh, vl;
#pragma unroll
        for (int j = 0; j < 8; ++j) {
            unsigned short hh = f2bf(f[j]);
            vh[j] = (short)hh;
            vl[j] = (short)f2bf(f[j] - bf2f(hh));
        }
        *reinterpret_cast<bf16x8*>(&A[b][0][srow][skf]) = vh;
        *reinterpret_cast<bf16x8*>(&A[b][1][srow][skf]) = vl;
    };
    auto compute = [&](int b, bf16x8 (&B)[8]) {
        bf16x8 ah = *reinterpret_cast<const bf16x8*>(&A[b][0][fr][kloc]);
        bf16x8 al = *reinterpret_cast<const bf16x8*>(&A[b][1][fr][kloc]);
#pragma unroll
        for (int et = 0; et < 4; ++et) {
            acc[et] = __builtin_amdgcn_mfma_f32_16x16x32_bf16(ah, B[et],     acc[et], 0, 0, 0);
            acc[et] = __builtin_amdgcn_mfma_f32_16x16x32_bf16(al, B[et],     acc[et], 0, 0, 0);
            acc[et] = __builtin_amdgcn_mfma_f32_16x16x32_bf16(ah, B[4 + et], acc[et], 0, 0, 0);
            acc[et] = __builtin_amdgcn_mfma_f32_16x16x32_bf16(al, B[4 + et], acc[et], 0, 0, 0);
        }
    };
    // iteration body: issue B(t+1) FIRST, then compute(t), stage(t+1), refill x(t+3)
    auto body = [&](int t, bf16x8 (&Bc)[8], bf16x8 (&Bn)[8],
                    float4 (&Xc)[2], int bc, int bn) {
        if (t + 1 < NT) loadB(Bn, t + 1);
        asm volatile("" ::: "memory");     // pin issue order: B before compute's waits
        compute(bc, Bc);
        if (t + 1 < NT) stage(bn, Xc);     // vmcnt-waits x(t+1): issued 2 iters ago
        if (t + 3 < NT) loadX(Xc, t + 3);  // refill consumed set
        asm volatile("" ::: "memory");
        __syncthreads();
    };

    // prologue: B(0); buf0 <- chunk0; X0 <- chunk1; X1 <- chunk2
    loadB(B0, 0);
    loadX(X0, 0);
    stage(0, X0);
    loadX(X0, 1);
    loadX(X1, 2);
    __syncthreads();

    for (int t = 0; t < NT; t += 2) {      // NT even; static ping-pong (rule #20)
        body(t,     B0, B1, X0, 0, 1);
        body(t + 1, B1, B0, X1, 1, 0);
    }

    // epilogue: per-slot partial logits into LDS (alias A), fused top-1 softmax
#pragma unroll
    for (int et = 0; et < 4; ++et)
#pragma unroll
        for (int r = 0; r < 4; ++r)
            // C/D layout: col = lane&15, row = (lane>>4)*4 + reg  [m89]
            L[kq][(lane >> 4) * 4 + r][et * 16 + fr] = acc[et][r];
    __syncthreads();

    {
        const int row = tid >> 4;   // 0..15
        const int eg  = tid & 15;   // 4 experts each
        float v[4];
#pragma unroll
        for (int j = 0; j < 4; ++j) {
            float s = L[0][row][eg * 4 + j];
#pragma unroll
            for (int q = 1; q < 4; ++q) s += L[q][row][eg * 4 + j];
            v[j] = s;
        }
        float m = v[0];
        int idx = eg * 4;
#pragma unroll
        for (int j = 1; j < 4; ++j)
            if (v[j] > m) { m = v[j]; idx = eg * 4 + j; }  // strict >: first occurrence
#pragma unroll
        for (int d = 1; d < 16; d <<= 1) {
            float om = __shfl_xor(m, d);
            int   oi = __shfl_xor(idx, d);
            if (om > m || (om == m && oi < idx)) { m = om; idx = oi; }
        }
        float s = 0.0f;
#pragma unroll
        for (int j = 0; j < 4; ++j) s += __expf(v[j] - m);
#pragma unroll
        for (int d = 1; d < 16; d <<= 1) s += __shfl_xor(s, d);
        if (eg == 0) {
            out[r0 + row]      = (float)idx;     // argmax index
            out[TN + r0 + row] = 1.0f / s;       // max gate = 1/sum(exp(l-lmax))
        }
    }
}

extern "C" void kernel_launch(void* const* d_in, const int* in_sizes, int n_in,
                              void* d_out, int out_size, void* d_ws, size_t ws_size,
                              hipStream_t stream) {
    const float* x  = (const float*)d_in[0];
    const float* wg = (const float*)d_in[1];
    float* out = (float*)d_out;

    unsigned short* BF = (unsigned short*)d_ws;  // 1 MB fragment-ordered hi/lo

    wg_frag_kernel<<<dim3(256), dim3(256), 0, stream>>>(wg, BF);
    gate_fused_kernel<<<dim3(TN / BM), dim3(256), 0, stream>>>(x, BF, out);
}